// Round 8
// baseline (449.337 us; speedup 1.0000x reference)
//
#include <hip/hip_runtime.h>
#include <hip/hip_bf16.h>

#define N_NODES 20000
#define N_REL 32
#define HID 128
#define EMB 16
#define N_EDGES 600000
#define NB (N_NODES * N_REL)   // 640000 bins

typedef __attribute__((ext_vector_type(8))) short  bf8v;   // 8 bf16 (MFMA A/B frag)
typedef __attribute__((ext_vector_type(8))) unsigned short us8v; // 16-byte unit
typedef __attribute__((ext_vector_type(4))) float  f4v;    // MFMA C/D frag

__device__ __forceinline__ unsigned short f2b(float f) {
    __hip_bfloat16 h = __float2bfloat16(f);
    return __builtin_bit_cast(unsigned short, h);
}
__device__ __forceinline__ float b2f(unsigned short u) {
    unsigned int x = ((unsigned int)u) << 16;
    return __builtin_bit_cast(float, x);
}

// ---- fused pass 1: histogram + all bf16 conversions/transposes ----
#define R_W2 (N_REL * HID * HID)        // 1048576
#define R_XB (N_NODES * 32)             // 640000
#define R_W1 (N_REL * HID * 32)         // 131072
#define R_R1 (HID * 32)                 // 4096
#define R_R2 (HID * HID)                // 16384
#define R_HIST N_EDGES                  // 600000
#define PRE_TOT (R_W2 + R_XB + R_W1 + R_R1 + R_R2 + R_HIST)

__global__ __launch_bounds__(256) void pre1_k(
    const int* __restrict__ dst, const int* __restrict__ et,
    const float* __restrict__ x, const float* __restrict__ W1,
    const float* __restrict__ root1, const float* __restrict__ W2,
    const float* __restrict__ root2,
    int* __restrict__ hist,
    unsigned short* __restrict__ xb, unsigned short* __restrict__ w1t,
    unsigned short* __restrict__ r1t, unsigned short* __restrict__ w2t,
    unsigned short* __restrict__ r2t) {
    int i = blockIdx.x * 256 + threadIdx.x;
    if (i < R_W2) {
        // coalesced read of W2 (r,k,n), scattered bf16 write to w2t (r,n,k)
        int r = i >> 14, k = (i >> 7) & 127, n = i & 127;
        w2t[(r << 14) + (n << 7) + k] = f2b(W2[i]);
        return;
    }
    i -= R_W2;
    if (i < R_XB) {
        int n = i >> 5, k = i & 31;
        xb[i] = (k < EMB) ? f2b(x[n * EMB + k]) : (unsigned short)0;
        return;
    }
    i -= R_XB;
    if (i < R_W1) {
        int r = i >> 12, n = (i >> 5) & 127, k = i & 31;
        w1t[i] = (k < EMB) ? f2b(W1[(r << 11) + (k << 7) + n]) : (unsigned short)0;
        return;
    }
    i -= R_W1;
    if (i < R_R1) {
        int n = i >> 5, k = i & 31;
        r1t[i] = (k < EMB) ? f2b(root1[(k << 7) + n]) : (unsigned short)0;
        return;
    }
    i -= R_R1;
    if (i < R_R2) {
        int n = i >> 7, k = i & 127;
        r2t[i] = f2b(root2[(k << 7) + n]);
        return;
    }
    i -= R_R2;
    if (i < R_HIST) atomicAdd(&hist[dst[i] * N_REL + et[i]], 1);
}

// ---- 2-level exclusive scan over NB = 625 blocks x 1024 (+ inv fused) ----
__global__ void scan1_k(const int* __restrict__ hist, int* __restrict__ binoff,
                        int* __restrict__ bsum, float* __restrict__ inv) {
    __shared__ int sh[256];
    const int t = threadIdx.x;
    const int base = blockIdx.x * 1024 + t * 4;
    int4 h4 = *(const int4*)(hist + base);
    float4 iv4;
    iv4.x = h4.x > 0 ? 1.0f / h4.x : 0.0f;
    iv4.y = h4.y > 0 ? 1.0f / h4.y : 0.0f;
    iv4.z = h4.z > 0 ? 1.0f / h4.z : 0.0f;
    iv4.w = h4.w > 0 ? 1.0f / h4.w : 0.0f;
    *(float4*)(inv + base) = iv4;
    int ts = h4.x + h4.y + h4.z + h4.w;
    sh[t] = ts;
    __syncthreads();
    for (int o = 1; o < 256; o <<= 1) {
        int v = (t >= o) ? sh[t - o] : 0;
        __syncthreads();
        sh[t] += v;
        __syncthreads();
    }
    int exc = sh[t] - ts;
    binoff[base + 0] = exc;
    binoff[base + 1] = exc + h4.x;
    binoff[base + 2] = exc + h4.x + h4.y;
    binoff[base + 3] = exc + h4.x + h4.y + h4.z;
    if (t == 255) bsum[blockIdx.x] = sh[255];
}

__global__ void scan2_k(const int* __restrict__ bsum, int* __restrict__ bbase) {
    __shared__ int sh[1024];
    const int t = threadIdx.x;
    int v = (t < 625) ? bsum[t] : 0;
    sh[t] = v;
    __syncthreads();
    for (int o = 1; o < 1024; o <<= 1) {
        int u = (t >= o) ? sh[t - o] : 0;
        __syncthreads();
        sh[t] += u;
        __syncthreads();
    }
    if (t < 625) bbase[t] = sh[t] - v;
}

__global__ void scan3_k(int* __restrict__ binoff, const int* __restrict__ bbase,
                        int* __restrict__ cursors) {
    int i = blockIdx.x * 256 + threadIdx.x;
    if (i < NB) {
        int v = binoff[i] + bbase[i >> 10];
        binoff[i] = v;
        cursors[i] = v;
    }
    if (i == 0) binoff[NB] = N_EDGES;
}

__global__ void scatter_k(const int* __restrict__ src, const int* __restrict__ dst,
                          const int* __restrict__ et, int* __restrict__ cursors,
                          int* __restrict__ ssrc) {
    int e = blockIdx.x * 256 + threadIdx.x;
    if (e < N_EDGES) {
        int b = dst[e] * N_REL + et[e];
        int p = atomicAdd(&cursors[b], 1);
        ssrc[p] = src[e];
    }
}

// ---- fused aggregate + transform GEMM ----
// grid (625, 2): block = 32 dst rows x 64 cols, 256 thr = 4 waves;
// wave w -> row tile 16*(w&1), col base blockIdx.y*64 + (w>>1)*32 (2 ct).
// Meta (binoff/inv for all 32 rows x 32 rels) preloaded to LDS once.
// Edge pipeline: at iter it (post-barrier) issue G-rows for it+1's first two
// edges (srcs loaded at it-1) + ssrc pair for it+2 — all independent loads,
// one full iteration to complete. Only cnt>=3 bins pay a serial chain.
// KT = K/32; LSS = LDS row stride (shorts, 16B-mult); CW = chunk width
// (shorts) per gather thread; NCH = (KT*32)/CW chunks/row; 32*NCH <= 256.
template<int KT, int LSS, int CW, bool L1>
__global__ __launch_bounds__(256) void gemm_k(
    const int* __restrict__ binoff, const float* __restrict__ inv,
    const int* __restrict__ ssrc,
    const unsigned short* __restrict__ G,    // bf16 rows [*, KT*32]
    const unsigned short* __restrict__ Bw,   // bf16 W^T [r][128][KT*32]
    const unsigned short* __restrict__ Br,   // bf16 root^T [128][KT*32]
    const float* __restrict__ bias,
    void* __restrict__ outp) {

    constexpr int ROW = KT * 32;
    constexpr int NCH = ROW / CW;
    constexpr int CP8 = CW / 8;
    static_assert(NCH * CW == ROW, "chunk covering must be exact");
    static_assert(32 * NCH <= 256, "one gather item per thread");

    __shared__ __align__(16) unsigned short As[2][32 * LSS];
    __shared__ int   smO[32 * N_REL + 1];
    __shared__ float smI[32 * N_REL];

    const int t = threadIdx.x;
    const int w = t >> 6, lane = t & 63;
    const int q = lane >> 4, m16 = lane & 15;
    const int d0 = blockIdx.x * 32;
    const int rowb = 16 * (w & 1);
    const int colb = blockIdx.y * 64 + (w >> 1) * 32;
    const bool gat = t < 32 * NCH;
    const int grow = t / NCH, gcc = t % NCH;
    const int mb = grow * N_REL;

    // ---- cooperative meta preload (contiguous bins for rows d0..d0+31) ----
    for (int i = t; i < 32 * N_REL + 1; i += 256) smO[i] = binoff[d0 * N_REL + i];
    for (int i = t; i < 32 * N_REL; i += 256) smI[i] = inv[d0 * N_REL + i];
    __syncthreads();

    f4v acc[2];
    acc[0] = f4v{0.f, 0.f, 0.f, 0.f};
    acc[1] = f4v{0.f, 0.f, 0.f, 0.f};

    // ---- prologue: prime the 2-deep edge pipeline for it=0 ----
    us8v gA[CP8], gB[CP8];
#pragma unroll
    for (int j = 0; j < CP8; ++j) { gA[j] = us8v{}; gB[j] = us8v{}; }
    int sx = 0, sy = 0;
    if (gat) {
        int so = smO[mb], cnt = smO[mb + 1] - so;
        if (cnt >= 1) sx = ssrc[so];
        if (cnt >= 2) sy = ssrc[so + 1];
        if (cnt >= 1) {
            const unsigned short* gp = G + (size_t)sx * ROW + gcc * CW;
#pragma unroll
            for (int j = 0; j < CP8; ++j) gA[j] = *(const us8v*)(gp + j * 8);
        }
        if (cnt >= 2) {
            const unsigned short* gp = G + (size_t)sy * ROW + gcc * CW;
#pragma unroll
            for (int j = 0; j < CP8; ++j) gB[j] = *(const us8v*)(gp + j * 8);
        }
        int so1 = smO[mb + 1], c1 = smO[mb + 2] - so1;
        if (c1 >= 1) sx = ssrc[so1];
        if (c1 >= 2) sy = ssrc[so1 + 1];
    }

    // B fragments for it=0
    bf8v bfr[2][KT];
#pragma unroll
    for (int ct = 0; ct < 2; ++ct) {
        const int n = colb + 16 * ct + m16;
#pragma unroll
        for (int ks = 0; ks < KT; ++ks)
            bfr[ct][ks] = *(const bf8v*)(Bw + (size_t)n * ROW + ks * 32 + q * 8);
    }

    for (int it = 0; it < N_REL; ++it) {
        unsigned short* Ab = As[it & 1];
        // ---- gather (consumes gA/gB primed last iteration) ----
        if (gat) {
            const int so = smO[mb + it], eo = smO[mb + it + 1];
            const int cnt = eo - so;
            float a[CW];
#pragma unroll
            for (int j = 0; j < CW; ++j) a[j] = 0.f;
            if (cnt >= 1) {
#pragma unroll
                for (int j = 0; j < CP8; ++j)
#pragma unroll
                    for (int k = 0; k < 8; ++k) a[j * 8 + k] += b2f(gA[j][k]);
            }
            if (cnt >= 2) {
#pragma unroll
                for (int j = 0; j < CP8; ++j)
#pragma unroll
                    for (int k = 0; k < 8; ++k) a[j * 8 + k] += b2f(gB[j][k]);
            }
            for (int p = so + 2; p < eo; ++p) {     // rare (P ~6%)
                const unsigned short* gp = G + (size_t)ssrc[p] * ROW + gcc * CW;
#pragma unroll
                for (int j = 0; j < CP8; ++j) {
                    us8v g = *(const us8v*)(gp + j * 8);
#pragma unroll
                    for (int k = 0; k < 8; ++k) a[j * 8 + k] += b2f(g[k]);
                }
            }
            const float iv = smI[mb + it];
            unsigned short* wp = &Ab[grow * LSS + gcc * CW];
#pragma unroll
            for (int j = 0; j < CP8; ++j) {
                us8v sv;
#pragma unroll
                for (int k = 0; k < 8; ++k) sv[k] = f2b(a[j * 8 + k] * iv);
                *(us8v*)(wp + j * 8) = sv;
            }
        }
        __syncthreads();

        // ---- post-barrier prefetch for it+1 / it+2 (independent loads) ----
        if (gat && it + 1 < N_REL) {
            const int c1 = smO[mb + it + 2] - smO[mb + it + 1];
            if (c1 >= 1) {
                const unsigned short* gp = G + (size_t)sx * ROW + gcc * CW;
#pragma unroll
                for (int j = 0; j < CP8; ++j) gA[j] = *(const us8v*)(gp + j * 8);
            }
            if (c1 >= 2) {
                const unsigned short* gp = G + (size_t)sy * ROW + gcc * CW;
#pragma unroll
                for (int j = 0; j < CP8; ++j) gB[j] = *(const us8v*)(gp + j * 8);
            }
            if (it + 2 < N_REL) {
                const int so2 = smO[mb + it + 2], c2 = smO[mb + it + 3] - so2;
                if (c2 >= 1) sx = ssrc[so2];
                if (c2 >= 2) sy = ssrc[so2 + 1];
            }
        }

        // ---- A fragments + MFMA (1 row tile x 2 col tiles per wave) ----
        const unsigned short* arp = &Ab[(rowb + m16) * LSS];
#pragma unroll
        for (int ks = 0; ks < KT; ++ks) {
            bf8v af = *(const bf8v*)(arp + ks * 32 + q * 8);
            acc[0] = __builtin_amdgcn_mfma_f32_16x16x32_bf16(af, bfr[0][ks], acc[0], 0, 0, 0);
            acc[1] = __builtin_amdgcn_mfma_f32_16x16x32_bf16(af, bfr[1][ks], acc[1], 0, 0, 0);
        }

        // ---- B fragments for it+1 (root weights after last relation) ----
        const unsigned short* Bp = (it + 1 < N_REL) ? (Bw + (size_t)(it + 1) * HID * ROW) : Br;
#pragma unroll
        for (int ct = 0; ct < 2; ++ct) {
            const int n = colb + 16 * ct + m16;
#pragma unroll
            for (int ks = 0; ks < KT; ++ks)
                bfr[ct][ks] = *(const bf8v*)(Bp + (size_t)n * ROW + ks * 32 + q * 8);
        }
    }

    // ---- root transform: A fragments straight from global ----
#pragma unroll
    for (int ks = 0; ks < KT; ++ks) {
        bf8v af = *(const bf8v*)(G + (size_t)(d0 + rowb + m16) * ROW + ks * 32 + q * 8);
        acc[0] = __builtin_amdgcn_mfma_f32_16x16x32_bf16(af, bfr[0][ks], acc[0], 0, 0, 0);
        acc[1] = __builtin_amdgcn_mfma_f32_16x16x32_bf16(af, bfr[1][ks], acc[1], 0, 0, 0);
    }

    // ---- epilogue: direct stores ----
#pragma unroll
    for (int ct = 0; ct < 2; ++ct) {
        const int col = colb + 16 * ct + m16;
        const float bc = bias[col];
#pragma unroll
        for (int g = 0; g < 4; ++g) {
            const int rr = rowb + q * 4 + g;
            if constexpr (L1) {
                ((unsigned short*)outp)[(size_t)(d0 + rr) * HID + col] =
                    f2b(fmaxf(acc[ct][g] + bc, 0.0f));
            } else {
                ((float*)outp)[(size_t)(d0 + rr) * HID + col] = acc[ct][g] + bc;
            }
        }
    }
}

extern "C" void kernel_launch(void* const* d_in, const int* in_sizes, int n_in,
                              void* d_out, int out_size, void* d_ws, size_t ws_size,
                              hipStream_t stream) {
    const int*   ei    = (const int*)d_in[0];   // [2, E]
    const int*   et    = (const int*)d_in[1];   // [E]
    const float* x     = (const float*)d_in[2]; // [N, 16]
    const float* W1    = (const float*)d_in[3]; // [32, 16, 128]
    const float* root1 = (const float*)d_in[4]; // [16, 128]
    const float* b1    = (const float*)d_in[5]; // [128]
    const float* W2    = (const float*)d_in[6]; // [32, 128, 128]
    const float* root2 = (const float*)d_in[7]; // [128, 128]
    const float* b2    = (const float*)d_in[8]; // [128]
    float* out = (float*)d_out;

    // ---- workspace layout ----
    char* ws = (char*)d_ws;
    size_t off = 0;
    auto alloc = [&](size_t bytes) { void* p = ws + off; off = (off + bytes + 63) & ~(size_t)63; return p; };
    int*   hist    = (int*)  alloc((size_t)NB * 4);
    int*   binoff  = (int*)  alloc((size_t)(NB + 1) * 4);
    int*   cursors = (int*)  alloc((size_t)NB * 4);
    float* inv     = (float*)alloc((size_t)NB * 4);
    int*   bsum    = (int*)  alloc(625 * 4);
    int*   bbase   = (int*)  alloc(625 * 4);
    int*   ssrc    = (int*)  alloc((size_t)(N_EDGES + 2) * 4);
    unsigned short* xb  = (unsigned short*)alloc((size_t)N_NODES * 32 * 2);
    unsigned short* h1b = (unsigned short*)alloc((size_t)N_NODES * HID * 2);
    unsigned short* w1t = (unsigned short*)alloc((size_t)N_REL * HID * 32 * 2);
    unsigned short* r1t = (unsigned short*)alloc((size_t)HID * 32 * 2);
    unsigned short* w2t = (unsigned short*)alloc((size_t)N_REL * HID * HID * 2);
    unsigned short* r2t = (unsigned short*)alloc((size_t)HID * HID * 2);

    const int* src = ei;
    const int* dst = ei + N_EDGES;

    hipMemsetAsync(hist, 0, (size_t)NB * 4, stream);

    // fused histogram + conversions
    pre1_k<<<(PRE_TOT + 255) / 256, 256, 0, stream>>>(
        dst, et, x, W1, root1, W2, root2, hist, xb, w1t, r1t, w2t, r2t);

    scan1_k<<<NB / 1024, 256, 0, stream>>>(hist, binoff, bsum, inv);
    scan2_k<<<1, 1024, 0, stream>>>(bsum, bbase);
    scan3_k<<<(NB + 255) / 256, 256, 0, stream>>>(binoff, bbase, cursors);
    scatter_k<<<(N_EDGES + 255) / 256, 256, 0, stream>>>(src, dst, et, cursors, ssrc);

    // layer 1: KT=1, LSS=40, CW=8 -> 4 chunks/row, 128 gather threads
    gemm_k<1, 40, 8, true><<<dim3(625, 2), 256, 0, stream>>>(
        binoff, inv, ssrc, xb, w1t, r1t, b1, h1b);

    // layer 2: KT=4, LSS=136, CW=16 -> 8 chunks/row, 256 gather threads
    gemm_k<4, 136, 16, false><<<dim3(625, 2), 256, 0, stream>>>(
        binoff, inv, ssrc, h1b, w2t, r2t, b2, out);
}

// Round 9
// 342.351 us; speedup vs baseline: 1.3125x; 1.3125x over previous
//
#include <hip/hip_runtime.h>
#include <hip/hip_bf16.h>

#define N_NODES 20000
#define N_REL 32
#define HID 128
#define EMB 16
#define N_EDGES 600000
#define NB (N_NODES * N_REL)   // 640000 bins

typedef __attribute__((ext_vector_type(8))) short  bf8v;   // 8 bf16 (MFMA A/B frag)
typedef __attribute__((ext_vector_type(8))) unsigned short us8v; // 16-byte unit
typedef __attribute__((ext_vector_type(4))) float  f4v;    // MFMA C/D frag

__device__ __forceinline__ unsigned short f2b(float f) {
    __hip_bfloat16 h = __float2bfloat16(f);
    return __builtin_bit_cast(unsigned short, h);
}
__device__ __forceinline__ float b2f(unsigned short u) {
    unsigned int x = ((unsigned int)u) << 16;
    return __builtin_bit_cast(float, x);
}

// ======== pre-pass: concat weight transposes + xb + histogram ========
// w2cat[n][k] (n<128, k<4224): k=r*128+kk -> W2[r][kk][n] (r<32), root2[kk][n] (r=32)
// w1cat[n][k] (k<1056): k=r*32+kk -> kk<16 ? W1/root1[kk][n] : 0
#define R_W2C (HID * 4224)      // 540672
#define R_W1C (HID * 1056)      // 135168
#define R_XB  (N_NODES * 32)    // 640000
#define R_HIST N_EDGES          // 600000
#define PRE_TOT (R_W2C + R_W1C + R_XB + R_HIST)

__global__ __launch_bounds__(256) void pre1_k(
    const int* __restrict__ dst, const int* __restrict__ et,
    const float* __restrict__ x, const float* __restrict__ W1,
    const float* __restrict__ root1, const float* __restrict__ W2,
    const float* __restrict__ root2,
    int* __restrict__ hist, unsigned short* __restrict__ xb,
    unsigned short* __restrict__ w1cat, unsigned short* __restrict__ w2cat) {
    int i = blockIdx.x * 256 + threadIdx.x;
    if (i < R_W2C) {
        int n = i / 4224, rem = i % 4224, r = rem >> 7, k = rem & 127;
        float v = (r < 32) ? W2[(r << 14) + (k << 7) + n] : root2[(k << 7) + n];
        w2cat[i] = f2b(v);
        return;
    }
    i -= R_W2C;
    if (i < R_W1C) {
        int n = i / 1056, rem = i % 1056, r = rem >> 5, k = rem & 31;
        float v = 0.0f;
        if (k < EMB) v = (r < 32) ? W1[(r << 11) + (k << 7) + n] : root1[(k << 7) + n];
        w1cat[i] = f2b(v);
        return;
    }
    i -= R_W1C;
    if (i < R_XB) {
        int n = i >> 5, k = i & 31;
        xb[i] = (k < EMB) ? f2b(x[n * EMB + k]) : (unsigned short)0;
        return;
    }
    i -= R_XB;
    if (i < R_HIST) atomicAdd(&hist[dst[i] * N_REL + et[i]], 1);
}

// ======== 2-level exclusive scan over NB = 625 x 1024 (+ inv fused) ========
__global__ void scan1_k(const int* __restrict__ hist, int* __restrict__ binoff,
                        int* __restrict__ bsum, float* __restrict__ inv) {
    __shared__ int sh[256];
    const int t = threadIdx.x;
    const int base = blockIdx.x * 1024 + t * 4;
    int4 h4 = *(const int4*)(hist + base);
    float4 iv4;
    iv4.x = h4.x > 0 ? 1.0f / h4.x : 0.0f;
    iv4.y = h4.y > 0 ? 1.0f / h4.y : 0.0f;
    iv4.z = h4.z > 0 ? 1.0f / h4.z : 0.0f;
    iv4.w = h4.w > 0 ? 1.0f / h4.w : 0.0f;
    *(float4*)(inv + base) = iv4;
    int ts = h4.x + h4.y + h4.z + h4.w;
    sh[t] = ts;
    __syncthreads();
    for (int o = 1; o < 256; o <<= 1) {
        int v = (t >= o) ? sh[t - o] : 0;
        __syncthreads();
        sh[t] += v;
        __syncthreads();
    }
    int exc = sh[t] - ts;
    binoff[base + 0] = exc;
    binoff[base + 1] = exc + h4.x;
    binoff[base + 2] = exc + h4.x + h4.y;
    binoff[base + 3] = exc + h4.x + h4.y + h4.z;
    if (t == 255) bsum[blockIdx.x] = sh[255];
}

__global__ void scan2_k(const int* __restrict__ bsum, int* __restrict__ bbase) {
    __shared__ int sh[1024];
    const int t = threadIdx.x;
    int v = (t < 625) ? bsum[t] : 0;
    sh[t] = v;
    __syncthreads();
    for (int o = 1; o < 1024; o <<= 1) {
        int u = (t >= o) ? sh[t - o] : 0;
        __syncthreads();
        sh[t] += u;
        __syncthreads();
    }
    if (t < 625) bbase[t] = sh[t] - v;
}

__global__ void scan3_k(int* __restrict__ binoff, const int* __restrict__ bbase,
                        int* __restrict__ cursors) {
    int i = blockIdx.x * 256 + threadIdx.x;
    if (i < NB) {
        int v = binoff[i] + bbase[i >> 10];
        binoff[i] = v;
        cursors[i] = v;
    }
    if (i == 0) binoff[NB] = N_EDGES;
}

__global__ void scatter_k(const int* __restrict__ src, const int* __restrict__ dst,
                          const int* __restrict__ et, int* __restrict__ cursors,
                          int* __restrict__ ssrc) {
    int e = blockIdx.x * 256 + threadIdx.x;
    if (e < N_EDGES) {
        int b = dst[e] * N_REL + et[e];
        int p = atomicAdd(&cursors[b], 1);
        ssrc[p] = src[e];
    }
}

// ======== aggregation: materialize Ag[d][33*SEGW] bf16 ========
// item i = (row, seg, 16B-chunk); seg<32: mean-aggregated gather; seg=32: copy G[d].
// Writes are exactly Ag[i*8..i*8+8) -> perfectly coalesced. Massive TLP hides
// the (binoff -> ssrc -> G) chain.
template<int SEGW>
__global__ __launch_bounds__(256) void agg_k(
    const int* __restrict__ binoff, const float* __restrict__ inv,
    const int* __restrict__ ssrc, const unsigned short* __restrict__ G,
    unsigned short* __restrict__ Ag, int rowBase, int nrows) {
    constexpr int CH = SEGW / 8;       // 16B chunks per segment
    constexpr int IPR = 33 * CH;       // items per row
    int i = blockIdx.x * 256 + threadIdx.x;
    if (i >= nrows * IPR) return;
    int d = rowBase + i / IPR;
    int rem = i % IPR;
    int seg = rem / CH, c = rem % CH;
    us8v v;
    if (seg < 32) {
        int b = d * N_REL + seg;
        int so = binoff[b], eo = binoff[b + 1];
        float a[8] = {0.f, 0.f, 0.f, 0.f, 0.f, 0.f, 0.f, 0.f};
        for (int p = so; p < eo; ++p) {
            us8v g = *(const us8v*)(G + (size_t)ssrc[p] * SEGW + c * 8);
#pragma unroll
            for (int k = 0; k < 8; ++k) a[k] += b2f(g[k]);
        }
        float iv = inv[b];
#pragma unroll
        for (int k = 0; k < 8; ++k) v[k] = f2b(a[k] * iv);
    } else {
        v = *(const us8v*)(G + (size_t)d * SEGW + c * 8);
    }
    *(us8v*)(Ag + (size_t)i * 8) = v;
}

// ======== dense GEMM: out[32 rows x 128 cols/block] = Ag @ Bcat + bias ========
// K = 33*SEGW in 33 tiles of SEGW. 2-stage A register prefetch + double-buffered
// LDS, one barrier/iter. B-frags (L2-hot Bcat) prefetched one iter ahead.
template<int KT, int LSS, bool L1>
__global__ __launch_bounds__(256) void gemm_d(
    const unsigned short* __restrict__ Ag,   // [nrows][33*SEGW] (chunk base)
    const unsigned short* __restrict__ Bcat, // [128][33*SEGW]
    const float* __restrict__ bias,
    void* __restrict__ outp, int rowBase) {
    constexpr int SEGW = KT * 32;
    constexpr int AK = 33 * SEGW;
    constexpr int NLD = 128 * KT;            // us8v loads per 32xSEGW A-tile
    constexpr int LPT = (NLD + 255) / 256;   // loads per thread (1 or 2)

    __shared__ __align__(16) unsigned short As[2][32 * LSS];

    const int t = threadIdx.x;
    const int w = t >> 6, lane = t & 63;
    const int q = lane >> 4, m16 = lane & 15;
    const int d0 = blockIdx.x * 32;
    const int colb = w * 32;

    // A-load assignment: load l covers (row = l/(4KT), chunk c = l%(4KT)) of the tile
    bool lact[LPT]; int lrow[LPT], lc[LPT];
    const unsigned short* abase[LPT];
#pragma unroll
    for (int j = 0; j < LPT; ++j) {
        int l = t + 256 * j;
        lact[j] = l < NLD;
        int li = lact[j] ? l : 0;
        lrow[j] = li / (4 * KT);
        lc[j]   = li % (4 * KT);
        abase[j] = Ag + (size_t)(d0 + lrow[j]) * AK + lc[j] * 8;
    }

    // prologue: A(0), A(1), B(0)
    us8v rA[LPT], rB[LPT];
#pragma unroll
    for (int j = 0; j < LPT; ++j) {
        rA[j] = lact[j] ? *(const us8v*)(abase[j]) : us8v{};
        rB[j] = lact[j] ? *(const us8v*)(abase[j] + SEGW) : us8v{};
    }
    bf8v bfr[2][KT];
#pragma unroll
    for (int ct = 0; ct < 2; ++ct) {
        const int n = colb + 16 * ct + m16;
#pragma unroll
        for (int ks = 0; ks < KT; ++ks)
            bfr[ct][ks] = *(const bf8v*)(Bcat + (size_t)n * AK + ks * 32 + q * 8);
    }

    f4v acc[2][2];
#pragma unroll
    for (int rt = 0; rt < 2; ++rt)
#pragma unroll
        for (int ct = 0; ct < 2; ++ct) acc[rt][ct] = f4v{0.f, 0.f, 0.f, 0.f};

    for (int it = 0; it < 33; ++it) {
        unsigned short* Ab = As[it & 1];
#pragma unroll
        for (int j = 0; j < LPT; ++j)
            if (lact[j]) *(us8v*)(&Ab[lrow[j] * LSS + lc[j] * 8]) = rA[j];
        __syncthreads();

        // advance pipeline: rA <- A(it+1); issue rB <- A(it+2)
#pragma unroll
        for (int j = 0; j < LPT; ++j) rA[j] = rB[j];
        if (it + 2 < 33) {
#pragma unroll
            for (int j = 0; j < LPT; ++j)
                if (lact[j]) rB[j] = *(const us8v*)(abase[j] + (size_t)(it + 2) * SEGW);
        }

        // MFMA over this K-tile
#pragma unroll
        for (int rt = 0; rt < 2; ++rt) {
            const unsigned short* ar = &Ab[(m16 + 16 * rt) * LSS];
#pragma unroll
            for (int ks = 0; ks < KT; ++ks) {
                bf8v af = *(const bf8v*)(ar + ks * 32 + q * 8);
                acc[rt][0] = __builtin_amdgcn_mfma_f32_16x16x32_bf16(af, bfr[0][ks], acc[rt][0], 0, 0, 0);
                acc[rt][1] = __builtin_amdgcn_mfma_f32_16x16x32_bf16(af, bfr[1][ks], acc[rt][1], 0, 0, 0);
            }
        }

        // B-frags for it+1 (consumed next iter; window = writes+barrier+A-issue)
        if (it + 1 < 33) {
            const unsigned short* Bp = Bcat + (size_t)(it + 1) * SEGW;
#pragma unroll
            for (int ct = 0; ct < 2; ++ct) {
                const int n = colb + 16 * ct + m16;
#pragma unroll
                for (int ks = 0; ks < KT; ++ks)
                    bfr[ct][ks] = *(const bf8v*)(Bp + (size_t)n * AK + ks * 32 + q * 8);
            }
        }
    }

    // epilogue: direct stores
#pragma unroll
    for (int ct = 0; ct < 2; ++ct) {
        const int col = colb + 16 * ct + m16;
        const float bc = bias[col];
#pragma unroll
        for (int rt = 0; rt < 2; ++rt) {
#pragma unroll
            for (int g = 0; g < 4; ++g) {
                const int rr = 16 * rt + q * 4 + g;
                const size_t orow = (size_t)(rowBase + d0 + rr);
                if constexpr (L1) {
                    ((unsigned short*)outp)[orow * HID + col] =
                        f2b(fmaxf(acc[rt][ct][g] + bc, 0.0f));
                } else {
                    ((float*)outp)[orow * HID + col] = acc[rt][ct][g] + bc;
                }
            }
        }
    }
}

extern "C" void kernel_launch(void* const* d_in, const int* in_sizes, int n_in,
                              void* d_out, int out_size, void* d_ws, size_t ws_size,
                              hipStream_t stream) {
    const int*   ei    = (const int*)d_in[0];   // [2, E]
    const int*   et    = (const int*)d_in[1];   // [E]
    const float* x     = (const float*)d_in[2]; // [N, 16]
    const float* W1    = (const float*)d_in[3]; // [32, 16, 128]
    const float* root1 = (const float*)d_in[4]; // [16, 128]
    const float* b1    = (const float*)d_in[5]; // [128]
    const float* W2    = (const float*)d_in[6]; // [32, 128, 128]
    const float* root2 = (const float*)d_in[7]; // [128, 128]
    const float* b2    = (const float*)d_in[8]; // [128]
    float* out = (float*)d_out;

    // ---- workspace layout ----
    char* ws = (char*)d_ws;
    size_t off = 0;
    auto alloc = [&](size_t bytes) { void* p = ws + off; off = (off + bytes + 63) & ~(size_t)63; return p; };
    int*   hist    = (int*)  alloc((size_t)NB * 4);
    int*   binoff  = (int*)  alloc((size_t)(NB + 1) * 4);
    int*   cursors = (int*)  alloc((size_t)NB * 4);
    float* inv     = (float*)alloc((size_t)NB * 4);
    int*   bsum    = (int*)  alloc(625 * 4);
    int*   bbase   = (int*)  alloc(625 * 4);
    int*   ssrc    = (int*)  alloc((size_t)(N_EDGES + 2) * 4);
    unsigned short* xb    = (unsigned short*)alloc((size_t)N_NODES * 32 * 2);
    unsigned short* h1b   = (unsigned short*)alloc((size_t)N_NODES * HID * 2);
    unsigned short* w1cat = (unsigned short*)alloc((size_t)R_W1C * 2);
    unsigned short* w2cat = (unsigned short*)alloc((size_t)R_W2C * 2);

    // remaining workspace -> Ag buffer (row-chunked if small)
    size_t avail = (ws_size > off) ? (ws_size - off) : 0;
    unsigned short* AgBuf = (unsigned short*)(ws + off);
    long long cap1 = (long long)(avail / (1056ULL * 2ULL));
    long long cap2 = (long long)(avail / (4224ULL * 2ULL));
    int rows1 = (cap1 >= N_NODES) ? N_NODES : (((int)cap1) & ~31);
    int rows2 = (cap2 >= N_NODES) ? N_NODES : (((int)cap2) & ~31);
    if (rows1 < 32) rows1 = 32;
    if (rows2 < 32) rows2 = 32;

    const int* src = ei;
    const int* dst = ei + N_EDGES;

    hipMemsetAsync(hist, 0, (size_t)NB * 4, stream);
    pre1_k<<<(PRE_TOT + 255) / 256, 256, 0, stream>>>(
        dst, et, x, W1, root1, W2, root2, hist, xb, w1cat, w2cat);
    scan1_k<<<NB / 1024, 256, 0, stream>>>(hist, binoff, bsum, inv);
    scan2_k<<<1, 1024, 0, stream>>>(bsum, bbase);
    scan3_k<<<(NB + 255) / 256, 256, 0, stream>>>(binoff, bbase, cursors);
    scatter_k<<<(N_EDGES + 255) / 256, 256, 0, stream>>>(src, dst, et, cursors, ssrc);

    // ---- layer 1: aggregate (SEGW=32) -> dense GEMM -> h1b (bf16 relu) ----
    for (int base = 0; base < N_NODES; base += rows1) {
        int rows = (N_NODES - base < rows1) ? (N_NODES - base) : rows1;
        int items = rows * 33 * 4;
        agg_k<32><<<(items + 255) / 256, 256, 0, stream>>>(
            binoff, inv, ssrc, xb, AgBuf, base, rows);
        gemm_d<1, 40, true><<<rows / 32, 256, 0, stream>>>(
            AgBuf, w1cat, b1, h1b, base);
    }

    // ---- layer 2: aggregate (SEGW=128) -> dense GEMM -> out (fp32) ----
    for (int base = 0; base < N_NODES; base += rows2) {
        int rows = (N_NODES - base < rows2) ? (N_NODES - base) : rows2;
        int items = rows * 33 * 16;
        agg_k<128><<<(items + 255) / 256, 256, 0, stream>>>(
            binoff, inv, ssrc, h1b, AgBuf, base, rows);
        gemm_d<4, 136, false><<<rows / 32, 256, 0, stream>>>(
            AgBuf, w2cat, b2, out, base);
    }
}

// Round 10
// 304.347 us; speedup vs baseline: 1.4764x; 1.1249x over previous
//
#include <hip/hip_runtime.h>
#include <hip/hip_bf16.h>

#define N_NODES 20000
#define N_REL 32
#define HID 128
#define EMB 16
#define N_EDGES 600000
#define NB (N_NODES * N_REL)   // 640000 bins

typedef __attribute__((ext_vector_type(8))) short  bf8v;   // 8 bf16 (MFMA A/B frag)
typedef __attribute__((ext_vector_type(8))) unsigned short us8v; // 16-byte unit
typedef __attribute__((ext_vector_type(4))) unsigned short us4v; // 8-byte unit
typedef __attribute__((ext_vector_type(4))) float  f4v;    // MFMA C/D frag

__device__ __forceinline__ unsigned short f2b(float f) {
    __hip_bfloat16 h = __float2bfloat16(f);
    return __builtin_bit_cast(unsigned short, h);
}
__device__ __forceinline__ float b2f(unsigned short u) {
    unsigned int x = ((unsigned int)u) << 16;
    return __builtin_bit_cast(float, x);
}

// ======== pre-pass: histogram + all bf16 conversions/transposes ========
#define R_W2 (N_REL * HID * HID)        // 1048576
#define R_XB (N_NODES * 32)             // 640000
#define R_W1 (N_REL * HID * 32)         // 131072
#define R_R1 (HID * 32)                 // 4096
#define R_R2 (HID * HID)                // 16384
#define R_HIST N_EDGES                  // 600000
#define PRE_TOT (R_W2 + R_XB + R_W1 + R_R1 + R_R2 + R_HIST)

__global__ __launch_bounds__(256) void pre1_k(
    const int* __restrict__ dst, const int* __restrict__ et,
    const float* __restrict__ x, const float* __restrict__ W1,
    const float* __restrict__ root1, const float* __restrict__ W2,
    const float* __restrict__ root2,
    int* __restrict__ hist,
    unsigned short* __restrict__ xb, unsigned short* __restrict__ w1t,
    unsigned short* __restrict__ r1t, unsigned short* __restrict__ w2t,
    unsigned short* __restrict__ r2t) {
    int i = blockIdx.x * 256 + threadIdx.x;
    if (i < R_W2) {
        // coalesced read of W2 (r,k,n) -> w2t[r][n][k]
        int r = i >> 14, k = (i >> 7) & 127, n = i & 127;
        w2t[(r << 14) + (n << 7) + k] = f2b(W2[i]);
        return;
    }
    i -= R_W2;
    if (i < R_XB) {
        int n = i >> 5, k = i & 31;
        xb[i] = (k < EMB) ? f2b(x[n * EMB + k]) : (unsigned short)0;
        return;
    }
    i -= R_XB;
    if (i < R_W1) {
        int r = i >> 12, n = (i >> 5) & 127, k = i & 31;
        w1t[i] = (k < EMB) ? f2b(W1[(r << 11) + (k << 7) + n]) : (unsigned short)0;
        return;
    }
    i -= R_W1;
    if (i < R_R1) {
        int n = i >> 5, k = i & 31;
        r1t[i] = (k < EMB) ? f2b(root1[(k << 7) + n]) : (unsigned short)0;
        return;
    }
    i -= R_R1;
    if (i < R_R2) {
        int n = i >> 7, k = i & 127;
        r2t[i] = f2b(root2[(k << 7) + n]);
        return;
    }
    i -= R_R2;
    if (i < R_HIST) atomicAdd(&hist[dst[i] * N_REL + et[i]], 1);
}

// ======== 2-level exclusive scan over NB = 625 x 1024 (+ inv fused) ========
__global__ void scan1_k(const int* __restrict__ hist, int* __restrict__ binoff,
                        int* __restrict__ bsum, float* __restrict__ inv) {
    __shared__ int sh[256];
    const int t = threadIdx.x;
    const int base = blockIdx.x * 1024 + t * 4;
    int4 h4 = *(const int4*)(hist + base);
    float4 iv4;
    iv4.x = h4.x > 0 ? 1.0f / h4.x : 0.0f;
    iv4.y = h4.y > 0 ? 1.0f / h4.y : 0.0f;
    iv4.z = h4.z > 0 ? 1.0f / h4.z : 0.0f;
    iv4.w = h4.w > 0 ? 1.0f / h4.w : 0.0f;
    *(float4*)(inv + base) = iv4;
    int ts = h4.x + h4.y + h4.z + h4.w;
    sh[t] = ts;
    __syncthreads();
    for (int o = 1; o < 256; o <<= 1) {
        int v = (t >= o) ? sh[t - o] : 0;
        __syncthreads();
        sh[t] += v;
        __syncthreads();
    }
    int exc = sh[t] - ts;
    binoff[base + 0] = exc;
    binoff[base + 1] = exc + h4.x;
    binoff[base + 2] = exc + h4.x + h4.y;
    binoff[base + 3] = exc + h4.x + h4.y + h4.z;
    if (t == 255) bsum[blockIdx.x] = sh[255];
}

__global__ void scan2_k(const int* __restrict__ bsum, int* __restrict__ bbase) {
    __shared__ int sh[1024];
    const int t = threadIdx.x;
    int v = (t < 625) ? bsum[t] : 0;
    sh[t] = v;
    __syncthreads();
    for (int o = 1; o < 1024; o <<= 1) {
        int u = (t >= o) ? sh[t - o] : 0;
        __syncthreads();
        sh[t] += u;
        __syncthreads();
    }
    if (t < 625) bbase[t] = sh[t] - v;
}

__global__ void scan3_k(int* __restrict__ binoff, const int* __restrict__ bbase,
                        int* __restrict__ cursors) {
    int i = blockIdx.x * 256 + threadIdx.x;
    if (i < NB) {
        int v = binoff[i] + bbase[i >> 10];
        binoff[i] = v;
        cursors[i] = v;
    }
    if (i == 0) binoff[NB] = N_EDGES;
}

__global__ void scatter_k(const int* __restrict__ src, const int* __restrict__ dst,
                          const int* __restrict__ et, int* __restrict__ cursors,
                          int* __restrict__ ssrc) {
    int e = blockIdx.x * 256 + threadIdx.x;
    if (e < N_EDGES) {
        int b = dst[e] * N_REL + et[e];
        int p = atomicAdd(&cursors[b], 1);
        ssrc[p] = src[e];
    }
}

// ======== fused aggregate+transform, RELATION-SPLIT, fp32 partials ========
// grid (625, NGRP) with NGRP = N_REL/RG groups. Block y handles relations
// [y*RG, y*RG+RG); the LAST group also adds the root transform. Block output
// is a full 32-row x 128-col fp32 partial -> part + y*N*HID (direct stores).
// Every relation's gather happens exactly once across the whole grid.
// Meta (binoff/inv for 32 rows x RG rels) preloaded to LDS; 2-deep edge
// pipeline (gA/gB regs + sx/sy next-src) issued post-barrier.
template<int KT, int LSS, int CW, int RG>
__global__ __launch_bounds__(256) void gemm_f(
    const int* __restrict__ binoff, const float* __restrict__ inv,
    const int* __restrict__ ssrc,
    const unsigned short* __restrict__ G,    // bf16 rows [*, KT*32]
    const unsigned short* __restrict__ Bw,   // bf16 W^T [r][128][KT*32]
    const unsigned short* __restrict__ Br,   // bf16 root^T [128][KT*32]
    float* __restrict__ part) {

    constexpr int ROW = KT * 32;
    constexpr int NCH = ROW / CW;
    constexpr int CP8 = CW / 8;
    static_assert(NCH * CW == ROW, "chunk covering must be exact");
    static_assert(32 * NCH <= 256, "one gather item per thread");

    __shared__ __align__(16) unsigned short As[2][32 * LSS];
    __shared__ int   smO[32 * (RG + 1)];
    __shared__ float smI[32 * RG];

    const int t = threadIdx.x;
    const int w = t >> 6, lane = t & 63;
    const int q = lane >> 4, m16 = lane & 15;
    const int d0 = blockIdx.x * 32;
    const int r0 = blockIdx.y * RG;
    const bool isLast = (r0 + RG >= N_REL);
    const int colb = w * 32;
    const bool gat = t < 32 * NCH;
    const int grow = t / NCH, gcc = t % NCH;
    const int mb  = grow * (RG + 1);
    const int mbI = grow * RG;

    // ---- meta preload (this group's bins only) ----
    for (int i = t; i < 32 * (RG + 1); i += 256) {
        int row = i / (RG + 1), rr = i % (RG + 1);
        smO[i] = binoff[(d0 + row) * N_REL + r0 + rr];
    }
    for (int i = t; i < 32 * RG; i += 256) {
        int row = i / RG, rr = i % RG;
        smI[i] = inv[(d0 + row) * N_REL + r0 + rr];
    }
    __syncthreads();

    f4v acc[2][2];
#pragma unroll
    for (int rt = 0; rt < 2; ++rt)
#pragma unroll
        for (int ct = 0; ct < 2; ++ct) acc[rt][ct] = f4v{0.f, 0.f, 0.f, 0.f};

    // ---- prologue: prime 2-deep edge pipeline for it=0 ----
    us8v gA[CP8], gB[CP8];
#pragma unroll
    for (int j = 0; j < CP8; ++j) { gA[j] = us8v{}; gB[j] = us8v{}; }
    int sx = 0, sy = 0;
    if (gat) {
        int so = smO[mb], cnt = smO[mb + 1] - so;
        if (cnt >= 1) sx = ssrc[so];
        if (cnt >= 2) sy = ssrc[so + 1];
        if (cnt >= 1) {
            const unsigned short* gp = G + (size_t)sx * ROW + gcc * CW;
#pragma unroll
            for (int j = 0; j < CP8; ++j) gA[j] = *(const us8v*)(gp + j * 8);
        }
        if (cnt >= 2) {
            const unsigned short* gp = G + (size_t)sy * ROW + gcc * CW;
#pragma unroll
            for (int j = 0; j < CP8; ++j) gB[j] = *(const us8v*)(gp + j * 8);
        }
        if (RG > 1) {
            int so1 = smO[mb + 1], c1 = smO[mb + 2] - so1;
            if (c1 >= 1) sx = ssrc[so1];
            if (c1 >= 2) sy = ssrc[so1 + 1];
        }
    }

    // B fragments for it=0
    bf8v bfr[2][KT];
#pragma unroll
    for (int ct = 0; ct < 2; ++ct) {
        const int n = colb + 16 * ct + m16;
#pragma unroll
        for (int ks = 0; ks < KT; ++ks)
            bfr[ct][ks] = *(const bf8v*)(Bw + ((size_t)r0 * HID + n) * ROW + ks * 32 + q * 8);
    }

    for (int it = 0; it < RG; ++it) {
        unsigned short* Ab = As[it & 1];
        // ---- gather (consumes gA/gB primed last iteration) ----
        if (gat) {
            const int so = smO[mb + it], eo = smO[mb + it + 1];
            const int cnt = eo - so;
            float a[CW];
#pragma unroll
            for (int j = 0; j < CW; ++j) a[j] = 0.f;
            if (cnt >= 1) {
#pragma unroll
                for (int j = 0; j < CP8; ++j)
#pragma unroll
                    for (int k = 0; k < 8; ++k) a[j * 8 + k] += b2f(gA[j][k]);
            }
            if (cnt >= 2) {
#pragma unroll
                for (int j = 0; j < CP8; ++j)
#pragma unroll
                    for (int k = 0; k < 8; ++k) a[j * 8 + k] += b2f(gB[j][k]);
            }
            for (int p = so + 2; p < eo; ++p) {     // rare tail (P ~6%)
                const unsigned short* gp = G + (size_t)ssrc[p] * ROW + gcc * CW;
#pragma unroll
                for (int j = 0; j < CP8; ++j) {
                    us8v g = *(const us8v*)(gp + j * 8);
#pragma unroll
                    for (int k = 0; k < 8; ++k) a[j * 8 + k] += b2f(g[k]);
                }
            }
            const float iv = smI[mbI + it];
            unsigned short* wp = &Ab[grow * LSS + gcc * CW];
#pragma unroll
            for (int j = 0; j < CP8; ++j) {
                us8v sv;
#pragma unroll
                for (int k = 0; k < 8; ++k) sv[k] = f2b(a[j * 8 + k] * iv);
                *(us8v*)(wp + j * 8) = sv;
            }
        }
        __syncthreads();

        // ---- post-barrier prefetch for it+1 / it+2 ----
        if (gat && it + 1 < RG) {
            const int c1 = smO[mb + it + 2] - smO[mb + it + 1];
            if (c1 >= 1) {
                const unsigned short* gp = G + (size_t)sx * ROW + gcc * CW;
#pragma unroll
                for (int j = 0; j < CP8; ++j) gA[j] = *(const us8v*)(gp + j * 8);
            }
            if (c1 >= 2) {
                const unsigned short* gp = G + (size_t)sy * ROW + gcc * CW;
#pragma unroll
                for (int j = 0; j < CP8; ++j) gB[j] = *(const us8v*)(gp + j * 8);
            }
            if (it + 2 < RG) {
                const int so2 = smO[mb + it + 2], c2 = smO[mb + it + 3] - so2;
                if (c2 >= 1) sx = ssrc[so2];
                if (c2 >= 2) sy = ssrc[so2 + 1];
            }
        }

        // ---- A fragments + MFMA ----
#pragma unroll
        for (int rt = 0; rt < 2; ++rt) {
            const unsigned short* ar = &Ab[(m16 + 16 * rt) * LSS];
#pragma unroll
            for (int ks = 0; ks < KT; ++ks) {
                bf8v af = *(const bf8v*)(ar + ks * 32 + q * 8);
                acc[rt][0] = __builtin_amdgcn_mfma_f32_16x16x32_bf16(af, bfr[0][ks], acc[rt][0], 0, 0, 0);
                acc[rt][1] = __builtin_amdgcn_mfma_f32_16x16x32_bf16(af, bfr[1][ks], acc[rt][1], 0, 0, 0);
            }
        }

        // ---- B fragments for it+1 (root weights after last relation of last group) ----
        const unsigned short* Bp = (it + 1 < RG) ? (Bw + (size_t)(r0 + it + 1) * HID * ROW)
                                                 : (isLast ? Br : nullptr);
        if (Bp) {
#pragma unroll
            for (int ct = 0; ct < 2; ++ct) {
                const int n = colb + 16 * ct + m16;
#pragma unroll
                for (int ks = 0; ks < KT; ++ks)
                    bfr[ct][ks] = *(const bf8v*)(Bp + (size_t)n * ROW + ks * 32 + q * 8);
            }
        }
    }

    // ---- root transform (last group only): A straight from global ----
    if (isLast) {
#pragma unroll
        for (int rt = 0; rt < 2; ++rt) {
#pragma unroll
            for (int ks = 0; ks < KT; ++ks) {
                bf8v af = *(const bf8v*)(G + (size_t)(d0 + m16 + 16 * rt) * ROW + ks * 32 + q * 8);
                acc[rt][0] = __builtin_amdgcn_mfma_f32_16x16x32_bf16(af, bfr[0][ks], acc[rt][0], 0, 0, 0);
                acc[rt][1] = __builtin_amdgcn_mfma_f32_16x16x32_bf16(af, bfr[1][ks], acc[rt][1], 0, 0, 0);
            }
        }
    }

    // ---- epilogue: direct fp32 partial stores ----
    float* pb = part + (size_t)blockIdx.y * N_NODES * HID;
#pragma unroll
    for (int ct = 0; ct < 2; ++ct) {
        const int col = colb + 16 * ct + m16;
#pragma unroll
        for (int rt = 0; rt < 2; ++rt) {
#pragma unroll
            for (int g = 0; g < 4; ++g) {
                const int rr = 16 * rt + q * 4 + g;
                pb[(size_t)(d0 + rr) * HID + col] = acc[rt][ct][g];
            }
        }
    }
}

// ======== reduces ========
__global__ __launch_bounds__(256) void reduce1_k(
    const float* __restrict__ part, const float* __restrict__ b1,
    unsigned short* __restrict__ h1b) {
    int i = blockIdx.x * 256 + threadIdx.x;   // float4 index
    if (i >= N_NODES * HID / 4) return;
    float4 a = ((const float4*)part)[i];
    float4 b = ((const float4*)(part + (size_t)N_NODES * HID))[i];
    float4 bb = *(const float4*)(b1 + ((i * 4) & 127));
    us4v v;
    v[0] = f2b(fmaxf(a.x + b.x + bb.x, 0.0f));
    v[1] = f2b(fmaxf(a.y + b.y + bb.y, 0.0f));
    v[2] = f2b(fmaxf(a.z + b.z + bb.z, 0.0f));
    v[3] = f2b(fmaxf(a.w + b.w + bb.w, 0.0f));
    *(us4v*)(h1b + (size_t)i * 4) = v;
}

__global__ __launch_bounds__(256) void reduce2_k(
    const float* __restrict__ part, const float* __restrict__ b2,
    float* __restrict__ out) {
    int i = blockIdx.x * 256 + threadIdx.x;   // float4 index
    if (i >= N_NODES * HID / 4) return;
    const size_t S = (size_t)N_NODES * HID;
    float4 a0 = ((const float4*)part)[i];
    float4 a1 = ((const float4*)(part + S))[i];
    float4 a2 = ((const float4*)(part + 2 * S))[i];
    float4 a3 = ((const float4*)(part + 3 * S))[i];
    float4 bb = *(const float4*)(b2 + ((i * 4) & 127));
    float4 r;
    r.x = (a0.x + a1.x) + (a2.x + a3.x) + bb.x;
    r.y = (a0.y + a1.y) + (a2.y + a3.y) + bb.y;
    r.z = (a0.z + a1.z) + (a2.z + a3.z) + bb.z;
    r.w = (a0.w + a1.w) + (a2.w + a3.w) + bb.w;
    ((float4*)out)[i] = r;
}

extern "C" void kernel_launch(void* const* d_in, const int* in_sizes, int n_in,
                              void* d_out, int out_size, void* d_ws, size_t ws_size,
                              hipStream_t stream) {
    const int*   ei    = (const int*)d_in[0];   // [2, E]
    const int*   et    = (const int*)d_in[1];   // [E]
    const float* x     = (const float*)d_in[2]; // [N, 16]
    const float* W1    = (const float*)d_in[3]; // [32, 16, 128]
    const float* root1 = (const float*)d_in[4]; // [16, 128]
    const float* b1    = (const float*)d_in[5]; // [128]
    const float* W2    = (const float*)d_in[6]; // [32, 128, 128]
    const float* root2 = (const float*)d_in[7]; // [128, 128]
    const float* b2    = (const float*)d_in[8]; // [128]
    float* out = (float*)d_out;

    // ---- workspace layout (~60 MB) ----
    char* ws = (char*)d_ws;
    size_t off = 0;
    auto alloc = [&](size_t bytes) { void* p = ws + off; off = (off + bytes + 63) & ~(size_t)63; return p; };
    int*   hist    = (int*)  alloc((size_t)NB * 4);
    int*   binoff  = (int*)  alloc((size_t)(NB + 1) * 4);
    int*   cursors = (int*)  alloc((size_t)NB * 4);
    float* inv     = (float*)alloc((size_t)NB * 4);
    int*   bsum    = (int*)  alloc(625 * 4);
    int*   bbase   = (int*)  alloc(625 * 4);
    int*   ssrc    = (int*)  alloc((size_t)(N_EDGES + 2) * 4);
    unsigned short* xb  = (unsigned short*)alloc((size_t)N_NODES * 32 * 2);
    unsigned short* h1b = (unsigned short*)alloc((size_t)N_NODES * HID * 2);
    unsigned short* w1t = (unsigned short*)alloc((size_t)N_REL * HID * 32 * 2);
    unsigned short* r1t = (unsigned short*)alloc((size_t)HID * 32 * 2);
    unsigned short* w2t = (unsigned short*)alloc((size_t)N_REL * HID * HID * 2);
    unsigned short* r2t = (unsigned short*)alloc((size_t)HID * HID * 2);
    float* part = (float*)alloc((size_t)4 * N_NODES * HID * 4);   // 4 partials, reused both layers

    const int* src = ei;
    const int* dst = ei + N_EDGES;

    hipMemsetAsync(hist, 0, (size_t)NB * 4, stream);
    pre1_k<<<(PRE_TOT + 255) / 256, 256, 0, stream>>>(
        dst, et, x, W1, root1, W2, root2, hist, xb, w1t, r1t, w2t, r2t);
    scan1_k<<<NB / 1024, 256, 0, stream>>>(hist, binoff, bsum, inv);
    scan2_k<<<1, 1024, 0, stream>>>(bsum, bbase);
    scan3_k<<<(NB + 255) / 256, 256, 0, stream>>>(binoff, bbase, cursors);
    scatter_k<<<(N_EDGES + 255) / 256, 256, 0, stream>>>(src, dst, et, cursors, ssrc);

    // ---- layer 1: 2 relation groups (16 rels each; last adds root) ----
    gemm_f<1, 40, 8, 16><<<dim3(625, 2), 256, 0, stream>>>(
        binoff, inv, ssrc, xb, w1t, r1t, part);
    reduce1_k<<<(N_NODES * HID / 4 + 255) / 256, 256, 0, stream>>>(part, b1, h1b);

    // ---- layer 2: 4 relation groups (8 rels each; last adds root) ----
    gemm_f<4, 136, 16, 8><<<dim3(625, 4), 256, 0, stream>>>(
        binoff, inv, ssrc, h1b, w2t, r2t, part);
    reduce2_k<<<(N_NODES * HID / 4 + 255) / 256, 256, 0, stream>>>(part, b2, out);
}